// Round 3
// baseline (136.939 us; speedup 1.0000x reference)
//
#include <hip/hip_runtime.h>
#include <stdint.h>

#pragma clang fp contract(off)

#define BS 32
#define NMAX 64
#define A_TOT 8400
#define NC 80

// ---- per-level top-9 selection (5x5 analytic window) + IoU at candidates ----
template<int N, int S, int START, int C0>
__device__ __forceinline__ void select_and_iou(
    int ilo, int jlo, float gcx, float gcy,
    float x1, float y1, float x2, float y2, float area_g,
    float* __restrict__ ovrow, int* __restrict__ idxrow)
{
  unsigned long long kk[9];
#pragma unroll
  for (int i = 0; i < 9; ++i) kk[i] = ~0ULL;
  const float s = (float)S;
#pragma unroll
  for (int di = 0; di < 5; ++di) {
    int ii = ilo + di;
    float ay = ((float)ii + 0.5f) * s;
    float dy = gcy - ay;
    float dy2 = dy * dy;
#pragma unroll
    for (int dj = 0; dj < 5; ++dj) {
      int jj = jlo + dj;
      float ax = ((float)jj + 0.5f) * s;
      float dx = gcx - ax;
      float d = sqrtf(dx * dx + dy2);           // ref op order: x^2 then +y^2
      unsigned long long key =
          ((unsigned long long)__float_as_uint(d) << 32) |
          (unsigned int)(START + ii * N + jj);  // (dist,idx) lex => top_k tie rule
      if (key < kk[8]) {
        kk[8] = key;
#pragma unroll
        for (int t = 8; t > 0; --t) {
          unsigned long long lo = kk[t], hi = kk[t - 1];
          if (lo < hi) { kk[t] = hi; kk[t - 1] = lo; }
        }
      }
    }
  }
#pragma unroll
  for (int t = 0; t < 9; ++t) {
    int aa = (int)(kk[t] & 0xffffffffULL);
    int loc = aa - START;
    int ii = loc / N;
    int jj = loc - ii * N;
    float cx = ((float)jj + 0.5f) * s;          // exact in f32
    float cy = ((float)ii + 0.5f) * s;
    const float h = 2.5f * (float)S;
    float ax1 = cx - h, ay1 = cy - h, ax2 = cx + h, ay2 = cy + h;
    float iw = fminf(x2, ax2) - fmaxf(x1, ax1); iw = fmaxf(iw, 0.f);
    float ih = fminf(y2, ay2) - fmaxf(y1, ay1); ih = fmaxf(ih, 0.f);
    float inter = iw * ih;
    float area_a = fmaxf(ax2 - ax1, 0.f) * fmaxf(ay2 - ay1, 0.f);
    float uni = fmaxf(area_g + area_a - inter, 1e-6f);
    ovrow[C0 + t] = inter / uni;
    idxrow[C0 + t] = aa;
  }
}

// ---- scatter positives of one level into the block's LDS window ----
template<int N, int S, int START, int C0>
__device__ __forceinline__ void scatter_level(
    const float* __restrict__ ovrow, const int* __restrict__ idxrow,
    float thr, float x1, float y1, float x2, float y2,
    int a0, int na, int g, int* s_cnt, int* s_gmin)
{
  const float s = (float)S;
#pragma unroll
  for (int t = 0; t < 9; ++t) {
    float o = ovrow[C0 + t];
    if (o > thr) {
      int aa = idxrow[C0 + t];
      if (aa >= a0 && aa < a0 + na) {
        int loc = aa - START;
        int ii = loc / N;
        int jj = loc - ii * N;
        float cx = ((float)jj + 0.5f) * s;
        float cy = ((float)ii + 0.5f) * s;
        float m = fminf(fminf(cx - x1, cy - y1), fminf(x2 - cx, y2 - cy));
        if (m > 1e-9f) {                        // strictly inside gt (EPS_GT)
          atomicAdd(&s_cnt[aa - a0], 1);
          atomicMin(&s_gmin[aa - a0], g);       // argmax first-max => lowest g
        }
      }
    }
  }
}

// =====================  Fused single kernel  ================================
// block = (anchor-window of 256, batch b). Phase 1: threads 0..63 redo the
// candidate selection for gts whose windows can touch this anchor window and
// scatter positives into LDS. Phase 2: per-anchor finalize + all outputs.

__global__ __launch_bounds__(256) void atss_fused_k(
    const int* __restrict__ gt_labels,
    const float* __restrict__ gt_bboxes,
    const float* __restrict__ mask_gt,
    const float* __restrict__ pd_bboxes,
    float* __restrict__ out)
{
  __shared__ float s_gt[NMAX * 4];
  __shared__ int   s_lab[NMAX];
  __shared__ float s_ov[NMAX][27];
  __shared__ int   s_idx[NMAX][27];
  __shared__ int   s_cnt[256];
  __shared__ int   s_gmin[256];
  __shared__ int   s_alab[256];
  __shared__ float s_asc[256];

  const int b   = blockIdx.y;
  const int a0  = blockIdx.x * 256;
  const int na  = min(256, A_TOT - a0);
  const int tid = threadIdx.x;

  s_gt[tid] = gt_bboxes[(size_t)b * NMAX * 4 + tid];   // 256 == NMAX*4
  if (tid < NMAX) s_lab[tid] = gt_labels[b * NMAX + tid];
  s_cnt[tid]  = 0;
  s_gmin[tid] = NMAX;
  __syncthreads();

  // ---------------- Phase 1: per-gt candidate selection + LDS scatter -------
  if (tid < NMAX) {
    const int g = tid;
    if (mask_gt[b * NMAX + g] > 0.0f) {
      float x1 = s_gt[g * 4 + 0], y1 = s_gt[g * 4 + 1];
      float x2 = s_gt[g * 4 + 2], y2 = s_gt[g * 4 + 3];
      float gcx = (x1 + x2) * 0.5f;
      float gcy = (y1 + y2) * 0.5f;

      int jlo0 = min(max((int)floorf(gcx / 8.f)  - 2, 0), 80 - 5);
      int ilo0 = min(max((int)floorf(gcy / 8.f)  - 2, 0), 80 - 5);
      int jlo1 = min(max((int)floorf(gcx / 16.f) - 2, 0), 40 - 5);
      int ilo1 = min(max((int)floorf(gcy / 16.f) - 2, 0), 40 - 5);
      int jlo2 = min(max((int)floorf(gcx / 32.f) - 2, 0), 20 - 5);
      int ilo2 = min(max((int)floorf(gcy / 32.f) - 2, 0), 20 - 5);

      // conservative candidate-index ranges per level vs this block's window
      int lo0 = ilo0 * 80 + jlo0,          hi0 = (ilo0 + 4) * 80 + jlo0 + 4;
      int lo1 = 6400 + ilo1 * 40 + jlo1,   hi1 = 6400 + (ilo1 + 4) * 40 + jlo1 + 4;
      int lo2 = 8000 + ilo2 * 20 + jlo2,   hi2 = 8000 + (ilo2 + 4) * 20 + jlo2 + 4;
      bool act = (lo0 < a0 + na && hi0 >= a0) ||
                 (lo1 < a0 + na && hi1 >= a0) ||
                 (lo2 < a0 + na && hi2 >= a0);

      if (act) {
        float area_g = fmaxf(x2 - x1, 0.f) * fmaxf(y2 - y1, 0.f);
        float* ovrow = s_ov[g];
        int*   idxrow = s_idx[g];
        select_and_iou<80,  8,    0,  0>(ilo0, jlo0, gcx, gcy, x1, y1, x2, y2, area_g, ovrow, idxrow);
        select_and_iou<40, 16, 6400,  9>(ilo1, jlo1, gcx, gcy, x1, y1, x2, y2, area_g, ovrow, idxrow);
        select_and_iou<20, 32, 8000, 18>(ilo2, jlo2, gcx, gcy, x1, y1, x2, y2, area_g, ovrow, idxrow);

        float sum = 0.f;
#pragma unroll
        for (int c = 0; c < 27; ++c) sum += ovrow[c];
        float mean = sum / 27.f;
        float ss = 0.f;
#pragma unroll
        for (int c = 0; c < 27; ++c) { float d = ovrow[c] - mean; ss += d * d; }
        float thr = mean + sqrtf(ss / 26.f);     // std ddof=1

        scatter_level<80,  8,    0,  0>(ovrow, idxrow, thr, x1, y1, x2, y2, a0, na, g, s_cnt, s_gmin);
        scatter_level<40, 16, 6400,  9>(ovrow, idxrow, thr, x1, y1, x2, y2, a0, na, g, s_cnt, s_gmin);
        scatter_level<20, 32, 8000, 18>(ovrow, idxrow, thr, x1, y1, x2, y2, a0, na, g, s_cnt, s_gmin);
      }
    }
  }
  __syncthreads();

  // ---------------- Phase 2: per-anchor finalize + outputs ------------------
  const int a = a0 + tid;
  int lab = NC; float sc = 0.f; int gsel = 0; int fg = 0;

  if (a < A_TOT) {
    const size_t ia = (size_t)b * A_TOT + a;
    const float4 pb = *(const float4*)(pd_bboxes + ia * 4);  // unconditional, coalesced
    const int c = s_cnt[tid];
    if (c == 1) { gsel = s_gmin[tid]; fg = 1; }
    else if (c > 1) {
      // contested: argmax over ALL 64 gts (incl. masked — ref semantics)
      float cx, cy, h;
      if (a < 6400)      { int ii = a / 80;          int jj = a - ii * 80;  cx = ((float)jj + 0.5f) * 8.f;  cy = ((float)ii + 0.5f) * 8.f;  h = 20.f; }
      else if (a < 8000) { int loc = a - 6400; int ii = loc / 40; int jj = loc - ii * 40; cx = ((float)jj + 0.5f) * 16.f; cy = ((float)ii + 0.5f) * 16.f; h = 40.f; }
      else               { int loc = a - 8000; int ii = loc / 20; int jj = loc - ii * 20; cx = ((float)jj + 0.5f) * 32.f; cy = ((float)ii + 0.5f) * 32.f; h = 80.f; }
      float ax1 = cx - h, ay1 = cy - h, ax2 = cx + h, ay2 = cy + h;
      float area_a = fmaxf(ax2 - ax1, 0.f) * fmaxf(ay2 - ay1, 0.f);
      float best = -1.f; int bg = 0;
      for (int gg = 0; gg < NMAX; ++gg) {
        float x1 = s_gt[gg * 4 + 0], y1 = s_gt[gg * 4 + 1];
        float x2 = s_gt[gg * 4 + 2], y2 = s_gt[gg * 4 + 3];
        float iw = fminf(x2, ax2) - fmaxf(x1, ax1); iw = fmaxf(iw, 0.f);
        float ih = fminf(y2, ay2) - fmaxf(y1, ay1); ih = fmaxf(ih, 0.f);
        float inter = iw * ih;
        float ag = fmaxf(x2 - x1, 0.f) * fmaxf(y2 - y1, 0.f);
        float uni = fmaxf(ag + area_a - inter, 1e-6f);
        float iou = inter / uni;
        if (iou > best) { best = iou; bg = gg; }  // first-max tie rule
      }
      gsel = bg; fg = 1;
    }

    if (fg) {
      lab = s_lab[gsel];
      float x1 = s_gt[gsel * 4 + 0], y1 = s_gt[gsel * 4 + 1];
      float x2 = s_gt[gsel * 4 + 2], y2 = s_gt[gsel * 4 + 3];
      float iw = fminf(x2, pb.z) - fmaxf(x1, pb.x); iw = fmaxf(iw, 0.f);
      float ih = fminf(y2, pb.w) - fmaxf(y1, pb.y); ih = fmaxf(ih, 0.f);
      float inter = iw * ih;
      float ag = fmaxf(x2 - x1, 0.f) * fmaxf(y2 - y1, 0.f);
      float ap = fmaxf(pb.z - pb.x, 0.f) * fmaxf(pb.w - pb.y, 0.f);
      sc = inter / (ag + ap - inter + 1e-9f);    // ref: no clamp, +1e-9 last
    }

    out[ia] = (float)lab;
    float4 bb = { s_gt[gsel * 4 + 0], s_gt[gsel * 4 + 1],
                  s_gt[gsel * 4 + 2], s_gt[gsel * 4 + 3] };
    *(float4*)(out + (size_t)BS * A_TOT + ia * 4) = bb;
    out[(size_t)BS * A_TOT * 85 + ia] = fg ? 1.0f : 0.0f;
  }

  s_alab[tid] = lab;
  s_asc[tid]  = sc;
  __syncthreads();

  // scores: one-hot(label)[:80] * sc — cooperative coalesced float4 writes
  float* outS = out + (size_t)BS * A_TOT * 5 + ((size_t)b * A_TOT + a0) * NC;
  const int nv4 = na * (NC / 4);
  for (int i = tid; i < nv4; i += 256) {
    int al = i / (NC / 4);
    int c4 = (i - al * (NC / 4)) * 4;
    int L  = s_alab[al];
    float sv = s_asc[al];
    float4 v;
    v.x = (L == c4 + 0) ? sv : 0.f;
    v.y = (L == c4 + 1) ? sv : 0.f;
    v.z = (L == c4 + 2) ? sv : 0.f;
    v.w = (L == c4 + 3) ? sv : 0.f;
    ((float4*)outS)[i] = v;
  }
}

// =============================  launcher  ====================================

extern "C" void kernel_launch(void* const* d_in, const int* in_sizes, int n_in,
                              void* d_out, int out_size, void* d_ws, size_t ws_size,
                              hipStream_t stream) {
  // d_in[0] = anc_bboxes (decoded analytically — unused)
  // d_in[1] = n_level_bboxes (static 6400/1600/400 — unused)
  const int*   gt_labels = (const int*)  d_in[2];
  const float* gt_bboxes = (const float*)d_in[3];
  const float* mask_gt   = (const float*)d_in[4];
  const float* pd_bboxes = (const float*)d_in[5];
  float* out = (float*)d_out;

  atss_fused_k<<<dim3((A_TOT + 255) / 256, BS), 256, 0, stream>>>(
      gt_labels, gt_bboxes, mask_gt, pd_bboxes, out);
}

// Round 9
// 127.872 us; speedup vs baseline: 1.0709x; 1.0709x over previous
//
#include <hip/hip_runtime.h>
#include <stdint.h>

#pragma clang fp contract(off)

#define BS 32
#define NMAX 64
#define A_TOT 8400
#define NC 80

typedef float vfloat4 __attribute__((ext_vector_type(4)));

// ---- per-level top-9 selection (5x5 analytic window) + IoU at candidates ----
template<int N, int S, int START, int C0>
__device__ __forceinline__ void select_and_iou(
    int ilo, int jlo, float gcx, float gcy,
    float x1, float y1, float x2, float y2, float area_g,
    float* __restrict__ ovrow, int* __restrict__ idxrow)
{
  unsigned long long kk[9];
#pragma unroll
  for (int i = 0; i < 9; ++i) kk[i] = ~0ULL;
  const float s = (float)S;
#pragma unroll
  for (int di = 0; di < 5; ++di) {
    int ii = ilo + di;
    float ay = ((float)ii + 0.5f) * s;
    float dy = gcy - ay;
    float dy2 = dy * dy;
#pragma unroll
    for (int dj = 0; dj < 5; ++dj) {
      int jj = jlo + dj;
      float ax = ((float)jj + 0.5f) * s;
      float dx = gcx - ax;
      float d = sqrtf(dx * dx + dy2);           // ref op order: x^2 then +y^2
      unsigned long long key =
          ((unsigned long long)__float_as_uint(d) << 32) |
          (unsigned int)(START + ii * N + jj);  // (dist,idx) lex => top_k tie rule
      if (key < kk[8]) {
        kk[8] = key;
#pragma unroll
        for (int t = 8; t > 0; --t) {
          unsigned long long lo = kk[t], hi = kk[t - 1];
          if (lo < hi) { kk[t] = hi; kk[t - 1] = lo; }
        }
      }
    }
  }
#pragma unroll
  for (int t = 0; t < 9; ++t) {
    int aa = (int)(kk[t] & 0xffffffffULL);
    int loc = aa - START;
    int ii = loc / N;
    int jj = loc - ii * N;
    float cx = ((float)jj + 0.5f) * s;          // exact in f32
    float cy = ((float)ii + 0.5f) * s;
    const float h = 2.5f * (float)S;
    float ax1 = cx - h, ay1 = cy - h, ax2 = cx + h, ay2 = cy + h;
    float iw = fminf(x2, ax2) - fmaxf(x1, ax1); iw = fmaxf(iw, 0.f);
    float ih = fminf(y2, ay2) - fmaxf(y1, ay1); ih = fmaxf(ih, 0.f);
    float inter = iw * ih;
    float area_a = fmaxf(ax2 - ax1, 0.f) * fmaxf(ay2 - ay1, 0.f);
    float uni = fmaxf(area_g + area_a - inter, 1e-6f);
    ovrow[C0 + t] = inter / uni;
    idxrow[C0 + t] = aa;
  }
}

// ---- scatter positives of one level into the block's LDS window ----
template<int N, int S, int START, int C0>
__device__ __forceinline__ void scatter_level(
    const float* __restrict__ ovrow, const int* __restrict__ idxrow,
    float thr, float x1, float y1, float x2, float y2,
    int a0, int na, int g, int* s_cnt, int* s_gmin)
{
  const float s = (float)S;
#pragma unroll
  for (int t = 0; t < 9; ++t) {
    float o = ovrow[C0 + t];
    if (o > thr) {
      int aa = idxrow[C0 + t];
      if (aa >= a0 && aa < a0 + na) {
        int loc = aa - START;
        int ii = loc / N;
        int jj = loc - ii * N;
        float cx = ((float)jj + 0.5f) * s;
        float cy = ((float)ii + 0.5f) * s;
        float m = fminf(fminf(cx - x1, cy - y1), fminf(x2 - cx, y2 - cy));
        if (m > 1e-9f) {                        // strictly inside gt (EPS_GT)
          atomicAdd(&s_cnt[aa - a0], 1);
          atomicMin(&s_gmin[aa - a0], g);       // argmax first-max => lowest g
        }
      }
    }
  }
}

// =====================  Fused single kernel  ================================
// block = (anchor-window of 256, batch b).
// Phase 0: thread g computes window coords + activity flag for gt g.
// Phase 1: 192 threads (3 levels x 64 gts) do selection+IoU in parallel.
// Phase 1b: 64 threads compute mean/std threshold and scatter to LDS atomics.
// Phase 2: per-anchor finalize + all outputs (nontemporal stores).

__global__ __launch_bounds__(256) void atss_fused_k(
    const int* __restrict__ gt_labels,
    const float* __restrict__ gt_bboxes,
    const float* __restrict__ mask_gt,
    const float* __restrict__ pd_bboxes,
    float* __restrict__ out)
{
  __shared__ float s_gt[NMAX * 4];
  __shared__ int   s_lab[NMAX];
  __shared__ float s_ov[NMAX][27];
  __shared__ int   s_idx[NMAX][27];
  __shared__ int   s_cnt[256];
  __shared__ int   s_gmin[256];
  __shared__ int   s_alab[256];
  __shared__ float s_asc[256];
  __shared__ short s_ilo[3][NMAX];
  __shared__ short s_jlo[3][NMAX];
  __shared__ unsigned char s_act[NMAX];

  const int b   = blockIdx.y;
  const int a0  = blockIdx.x * 256;
  const int na  = min(256, A_TOT - a0);
  const int tid = threadIdx.x;

  s_gt[tid] = gt_bboxes[(size_t)b * NMAX * 4 + tid];   // 256 == NMAX*4
  if (tid < NMAX) s_lab[tid] = gt_labels[b * NMAX + tid];
  s_cnt[tid]  = 0;
  s_gmin[tid] = NMAX;
  __syncthreads();

  // ---------------- Phase 0: per-gt window + activity ----------------------
  if (tid < NMAX) {
    const int g = tid;
    bool act = false;
    if (mask_gt[b * NMAX + g] > 0.0f) {
      float x1 = s_gt[g * 4 + 0], y1 = s_gt[g * 4 + 1];
      float x2 = s_gt[g * 4 + 2], y2 = s_gt[g * 4 + 3];
      float gcx = (x1 + x2) * 0.5f;
      float gcy = (y1 + y2) * 0.5f;

      int jlo0 = min(max((int)floorf(gcx / 8.f)  - 2, 0), 80 - 5);
      int ilo0 = min(max((int)floorf(gcy / 8.f)  - 2, 0), 80 - 5);
      int jlo1 = min(max((int)floorf(gcx / 16.f) - 2, 0), 40 - 5);
      int ilo1 = min(max((int)floorf(gcy / 16.f) - 2, 0), 40 - 5);
      int jlo2 = min(max((int)floorf(gcx / 32.f) - 2, 0), 20 - 5);
      int ilo2 = min(max((int)floorf(gcy / 32.f) - 2, 0), 20 - 5);
      s_jlo[0][g] = (short)jlo0; s_ilo[0][g] = (short)ilo0;
      s_jlo[1][g] = (short)jlo1; s_ilo[1][g] = (short)ilo1;
      s_jlo[2][g] = (short)jlo2; s_ilo[2][g] = (short)ilo2;

      // conservative candidate-index ranges per level vs this block's window
      int lo0 = ilo0 * 80 + jlo0,          hi0 = (ilo0 + 4) * 80 + jlo0 + 4;
      int lo1 = 6400 + ilo1 * 40 + jlo1,   hi1 = 6400 + (ilo1 + 4) * 40 + jlo1 + 4;
      int lo2 = 8000 + ilo2 * 20 + jlo2,   hi2 = 8000 + (ilo2 + 4) * 20 + jlo2 + 4;
      act = (lo0 < a0 + na && hi0 >= a0) ||
            (lo1 < a0 + na && hi1 >= a0) ||
            (lo2 < a0 + na && hi2 >= a0);
    }
    s_act[tid] = act ? 1 : 0;
  }
  __syncthreads();

  // ---------------- Phase 1: selection + IoU, 3 levels in parallel ---------
  if (tid < 192) {
    const int g  = tid & 63;
    const int lv = tid >> 6;
    if (s_act[g]) {
      float x1 = s_gt[g * 4 + 0], y1 = s_gt[g * 4 + 1];
      float x2 = s_gt[g * 4 + 2], y2 = s_gt[g * 4 + 3];
      float gcx = (x1 + x2) * 0.5f;
      float gcy = (y1 + y2) * 0.5f;
      float area_g = fmaxf(x2 - x1, 0.f) * fmaxf(y2 - y1, 0.f);
      float* ovrow  = s_ov[g];
      int*   idxrow = s_idx[g];
      int ilo = s_ilo[lv][g], jlo = s_jlo[lv][g];
      if (lv == 0)
        select_and_iou<80,  8,    0,  0>(ilo, jlo, gcx, gcy, x1, y1, x2, y2, area_g, ovrow, idxrow);
      else if (lv == 1)
        select_and_iou<40, 16, 6400,  9>(ilo, jlo, gcx, gcy, x1, y1, x2, y2, area_g, ovrow, idxrow);
      else
        select_and_iou<20, 32, 8000, 18>(ilo, jlo, gcx, gcy, x1, y1, x2, y2, area_g, ovrow, idxrow);
    }
  }
  __syncthreads();

  // ---------------- Phase 1b: threshold + scatter (64 threads) -------------
  if (tid < NMAX && s_act[tid]) {
    const int g = tid;
    float x1 = s_gt[g * 4 + 0], y1 = s_gt[g * 4 + 1];
    float x2 = s_gt[g * 4 + 2], y2 = s_gt[g * 4 + 3];
    const float* ovrow  = s_ov[g];
    const int*   idxrow = s_idx[g];

    float sum = 0.f;
#pragma unroll
    for (int c = 0; c < 27; ++c) sum += ovrow[c];
    float mean = sum / 27.f;
    float ss = 0.f;
#pragma unroll
    for (int c = 0; c < 27; ++c) { float d = ovrow[c] - mean; ss += d * d; }
    float thr = mean + sqrtf(ss / 26.f);         // std ddof=1

    scatter_level<80,  8,    0,  0>(ovrow, idxrow, thr, x1, y1, x2, y2, a0, na, g, s_cnt, s_gmin);
    scatter_level<40, 16, 6400,  9>(ovrow, idxrow, thr, x1, y1, x2, y2, a0, na, g, s_cnt, s_gmin);
    scatter_level<20, 32, 8000, 18>(ovrow, idxrow, thr, x1, y1, x2, y2, a0, na, g, s_cnt, s_gmin);
  }
  __syncthreads();

  // ---------------- Phase 2: per-anchor finalize + outputs ------------------
  const int a = a0 + tid;
  int lab = NC; float sc = 0.f; int gsel = 0; int fg = 0;

  if (a < A_TOT) {
    const size_t ia = (size_t)b * A_TOT + a;
    const float4 pb = *(const float4*)(pd_bboxes + ia * 4);  // coalesced
    const int c = s_cnt[tid];
    if (c == 1) { gsel = s_gmin[tid]; fg = 1; }
    else if (c > 1) {
      // contested: argmax over ALL 64 gts (incl. masked — ref semantics)
      float cx, cy, h;
      if (a < 6400)      { int ii = a / 80;          int jj = a - ii * 80;  cx = ((float)jj + 0.5f) * 8.f;  cy = ((float)ii + 0.5f) * 8.f;  h = 20.f; }
      else if (a < 8000) { int loc = a - 6400; int ii = loc / 40; int jj = loc - ii * 40; cx = ((float)jj + 0.5f) * 16.f; cy = ((float)ii + 0.5f) * 16.f; h = 40.f; }
      else               { int loc = a - 8000; int ii = loc / 20; int jj = loc - ii * 20; cx = ((float)jj + 0.5f) * 32.f; cy = ((float)ii + 0.5f) * 32.f; h = 80.f; }
      float ax1 = cx - h, ay1 = cy - h, ax2 = cx + h, ay2 = cy + h;
      float area_a = fmaxf(ax2 - ax1, 0.f) * fmaxf(ay2 - ay1, 0.f);
      float best = -1.f; int bg = 0;
      for (int gg = 0; gg < NMAX; ++gg) {
        float x1 = s_gt[gg * 4 + 0], y1 = s_gt[gg * 4 + 1];
        float x2 = s_gt[gg * 4 + 2], y2 = s_gt[gg * 4 + 3];
        float iw = fminf(x2, ax2) - fmaxf(x1, ax1); iw = fmaxf(iw, 0.f);
        float ih = fminf(y2, ay2) - fmaxf(y1, ay1); ih = fmaxf(ih, 0.f);
        float inter = iw * ih;
        float ag = fmaxf(x2 - x1, 0.f) * fmaxf(y2 - y1, 0.f);
        float uni = fmaxf(ag + area_a - inter, 1e-6f);
        float iou = inter / uni;
        if (iou > best) { best = iou; bg = gg; }  // first-max tie rule
      }
      gsel = bg; fg = 1;
    }

    if (fg) {
      lab = s_lab[gsel];
      float x1 = s_gt[gsel * 4 + 0], y1 = s_gt[gsel * 4 + 1];
      float x2 = s_gt[gsel * 4 + 2], y2 = s_gt[gsel * 4 + 3];
      float iw = fminf(x2, pb.z) - fmaxf(x1, pb.x); iw = fmaxf(iw, 0.f);
      float ih = fminf(y2, pb.w) - fmaxf(y1, pb.y); ih = fmaxf(ih, 0.f);
      float inter = iw * ih;
      float ag = fmaxf(x2 - x1, 0.f) * fmaxf(y2 - y1, 0.f);
      float ap = fmaxf(pb.z - pb.x, 0.f) * fmaxf(pb.w - pb.y, 0.f);
      sc = inter / (ag + ap - inter + 1e-9f);    // ref: no clamp, +1e-9 last
    }

    __builtin_nontemporal_store((float)lab, out + ia);
    vfloat4 bb = { s_gt[gsel * 4 + 0], s_gt[gsel * 4 + 1],
                   s_gt[gsel * 4 + 2], s_gt[gsel * 4 + 3] };
    __builtin_nontemporal_store(bb, (vfloat4*)(out + (size_t)BS * A_TOT + ia * 4));
    __builtin_nontemporal_store(fg ? 1.0f : 0.0f, out + (size_t)BS * A_TOT * 85 + ia);
  }

  s_alab[tid] = lab;
  s_asc[tid]  = sc;
  __syncthreads();

  // scores: one-hot(label)[:80] * sc — cooperative coalesced float4 nt-stores
  float* outS = out + (size_t)BS * A_TOT * 5 + ((size_t)b * A_TOT + a0) * NC;
  const int nv4 = na * (NC / 4);
  for (int i = tid; i < nv4; i += 256) {
    int al = i / (NC / 4);
    int c4 = (i - al * (NC / 4)) * 4;
    int L  = s_alab[al];
    float sv = s_asc[al];
    vfloat4 v;
    v.x = (L == c4 + 0) ? sv : 0.f;
    v.y = (L == c4 + 1) ? sv : 0.f;
    v.z = (L == c4 + 2) ? sv : 0.f;
    v.w = (L == c4 + 3) ? sv : 0.f;
    __builtin_nontemporal_store(v, ((vfloat4*)outS) + i);
  }
}

// =============================  launcher  ====================================

extern "C" void kernel_launch(void* const* d_in, const int* in_sizes, int n_in,
                              void* d_out, int out_size, void* d_ws, size_t ws_size,
                              hipStream_t stream) {
  // d_in[0] = anc_bboxes (decoded analytically — unused)
  // d_in[1] = n_level_bboxes (static 6400/1600/400 — unused)
  const int*   gt_labels = (const int*)  d_in[2];
  const float* gt_bboxes = (const float*)d_in[3];
  const float* mask_gt   = (const float*)d_in[4];
  const float* pd_bboxes = (const float*)d_in[5];
  float* out = (float*)d_out;

  atss_fused_k<<<dim3((A_TOT + 255) / 256, BS), 256, 0, stream>>>(
      gt_labels, gt_bboxes, mask_gt, pd_bboxes, out);
}